// Round 16
// baseline (434.557 us; speedup 1.0000x reference)
//
#include <hip/hip_runtime.h>
#include <hip/hip_bf16.h>

#define HID 256
#define LN_EPS 1e-5f
#define DENOM_EPS 1e-8f

typedef __attribute__((ext_vector_type(8))) short short8;
typedef __attribute__((ext_vector_type(4))) float f32x4;

#define WP1_ELEMS (28 * 256 * 32)   // K=896 packed, pre-scaled by 0.5
#define WP2_ELEMS (24 * 256 * 32)   // K=768 (3 rels x 256)

__device__ inline unsigned bfpk(float x, float y) {
    __hip_bfloat162 h = __float22bfloat162_rn(make_float2(x, y));
    return *reinterpret_cast<unsigned*>(&h);
}

__device__ inline void gld16(const void* g, void* l) {
    __builtin_amdgcn_global_load_lds(
        (const __attribute__((address_space(1))) void*)g,
        (__attribute__((address_space(3))) void*)l, 16, 0, 0);
}

__device__ inline f32x4 bf4_to_f32(uint2 p) {
    union { float f; unsigned u; } c;
    f32x4 r;
    c.u = (p.x & 0xFFFFu) << 16;  r[0] = c.f;
    c.u = (p.x & 0xFFFF0000u);    r[1] = c.f;
    c.u = (p.y & 0xFFFFu) << 16;  r[2] = c.f;
    c.u = (p.y & 0xFFFF0000u);    r[3] = c.f;
    return r;
}

// Pack weights: wp[ks32][col][kk] = W[ks32*32+kk][col] (*0.5 for wp1)
__global__ __launch_bounds__(256) void kpack(
    const float* __restrict__ wt, const float* __restrict__ wi,
    const float* __restrict__ wrel,
    __hip_bfloat16* __restrict__ wp1, __hip_bfloat16* __restrict__ wp2)
{
    int idx = blockIdx.x * 256 + threadIdx.x;
    if (idx < WP1_ELEMS) {
        int kk = idx & 31, col = (idx >> 5) & 255, ks = idx >> 13;
        int k = ks * 32 + kk;
        float v = (k < 384) ? wt[k * 256 + col] : wi[(k - 384) * 256 + col];
        wp1[idx] = __float2bfloat16(v * 0.5f);
    } else {
        int j = idx - WP1_ELEMS;
        if (j < WP2_ELEMS) {
            int kk = j & 31, col = (j >> 5) & 255, ks = j >> 13;
            int k = ks * 32 + kk;
            wp2[j] = __float2bfloat16(wrel[k * 256 + col]);
        }
    }
}

__global__ __launch_bounds__(256) void kchain(
    const int* __restrict__ edst, int* __restrict__ head, int* __restrict__ nxt, int E)
{
    int e = blockIdx.x * 256 + threadIdx.x;
    if (e < E) nxt[e] = atomicExch(&head[edst[e]], e);
}

// k2: 8 waves/block, one dst node per wave. Gathers BF16 h0 rows (512B/edge).
// S[d][rel*256+c] = bf16(acc[rel][c] / max(denom[rel], eps)), row-major [N][768].
__global__ __launch_bounds__(512) void k2_gather(
    const __hip_bfloat16* __restrict__ h0b, const int* __restrict__ esrc,
    const int* __restrict__ etype, const float* __restrict__ ew,
    const int* __restrict__ head, const int* __restrict__ nxt,
    __hip_bfloat16* __restrict__ S, int N)
{
    int w = threadIdx.x >> 6;
    int lane = threadIdx.x & 63;
    int d = blockIdx.x * 8 + w;
    if (d >= N) return;

    f32x4 a0 = {0.f, 0.f, 0.f, 0.f}, a1 = a0, a2 = a0;
    float d0 = 0.f, d1 = 0.f, d2 = 0.f;

    int e = head[d];
    while (e >= 0) {
        int src = esrc[e];
        int ty = etype[e];          // wave-uniform
        float we = ew[e];
        uint2 hv = *(const uint2*)(h0b + (size_t)src * HID + lane * 4);
        f32x4 h = bf4_to_f32(hv);
        if (ty == 0)      { a0 += we * h; d0 += we; }
        else if (ty == 1) { a1 += we * h; d1 += we; }
        else              { a2 += we * h; d2 += we; }
        e = nxt[e];
    }

    float i0 = 1.0f / fmaxf(d0, DENOM_EPS);
    float i1 = 1.0f / fmaxf(d1, DENOM_EPS);
    float i2 = 1.0f / fmaxf(d2, DENOM_EPS);
    __hip_bfloat16* row = S + (size_t)d * 768;
    uint2 p;
    p = make_uint2(bfpk(a0[0] * i0, a0[1] * i0), bfpk(a0[2] * i0, a0[3] * i0));
    *(uint2*)(row + 0   + lane * 4) = p;
    p = make_uint2(bfpk(a1[0] * i1, a1[1] * i1), bfpk(a1[2] * i1, a1[3] * i1));
    *(uint2*)(row + 256 + lane * 4) = p;
    p = make_uint2(bfpk(a2[0] * i2, a2[1] * i2), bfpk(a2[2] * i2, a2[3] * i2));
    *(uint2*)(row + 512 + lane * 4) = p;
}

// kg0: h0b = bf16(ft@wp1a + fi@wp1b) (0.5 pre-folded), row 0 zeroed.
// R8 loop verbatim. C-WRITE THROUGH LDS: scatter acc into a 32-row x 528B-stride
// bf16 tile (stride breaks bank conflicts), re-read row-major, packed short8
// global stores (full-line writes, no RMW). Two halves to fit 24KB LDS.
__global__ __launch_bounds__(256, 4) void kg0(
    const float* __restrict__ ft, const float* __restrict__ fi,
    const __hip_bfloat16* __restrict__ wp,
    __hip_bfloat16* __restrict__ h0b, int N)
{
    constexpr int NSTEPS = 28;
    __shared__ __align__(16) unsigned char As[3][8192];

    const int t = threadIdx.x;
    const int lane = t & 63;
    const int w = t >> 6;
    const int m0 = blockIdx.x * 64;
    const int g = lane >> 4;
    const int rl = lane & 15;

    auto stageA = [&](int ks, int buf) {
#pragma unroll
        for (int j = 0; j < 2; ++j) {
            int slot = j * 4 + w;
            int r = slot * 8 + (lane >> 3);
            int grow = m0 + r; if (grow >= N) grow = m0;
            int q = (lane & 7) ^ (lane >> 3);
            const float* src = (ks < 12)
                ? (ft + (size_t)grow * 384 + ks * 32 + q * 4)
                : (fi + (size_t)grow * 512 + (ks - 12) * 32 + q * 4);
            gld16(src, As[buf] + slot * 1024);
        }
    };
    auto loadB = [&](short8 (&bf)[4], int ks) {
#pragma unroll
        for (int fc = 0; fc < 4; ++fc)
            bf[fc] = *(const short8*)((const short*)wp +
                      (size_t)(ks * 256 + w * 64 + fc * 16 + rl) * 32 + g * 8);
    };

    f32x4 acc[4][4];
#pragma unroll
    for (int i = 0; i < 4; ++i)
#pragma unroll
        for (int j = 0; j < 4; ++j) acc[i][j] = (f32x4){0.f, 0.f, 0.f, 0.f};

    auto compute = [&](int ks, short8 (&bf)[4]) {
        const unsigned char* Ab = As[ks % 3];
        short8 af[4];
#pragma unroll
        for (int fr = 0; fr < 4; ++fr) {
            int r = fr * 16 + rl;
            const unsigned char* base = Ab + r * 128;
            f32x4 lo = *(const f32x4*)(base + ((2 * g) ^ (r & 7)) * 16);
            f32x4 hi = *(const f32x4*)(base + ((2 * g + 1) ^ (r & 7)) * 16);
            union { short8 s8; unsigned u[4]; } cv;
            cv.u[0] = bfpk(lo[0], lo[1]);
            cv.u[1] = bfpk(lo[2], lo[3]);
            cv.u[2] = bfpk(hi[0], hi[1]);
            cv.u[3] = bfpk(hi[2], hi[3]);
            af[fr] = cv.s8;
        }
#pragma unroll
        for (int fr = 0; fr < 4; ++fr)
#pragma unroll
            for (int fc = 0; fc < 4; ++fc)
                acc[fr][fc] = __builtin_amdgcn_mfma_f32_16x16x32_bf16(af[fr], bf[fc], acc[fr][fc], 0, 0, 0);
    };

    short8 bfe[4], bfo[4];
    stageA(0, 0);
    stageA(1, 1);
    loadB(bfe, 0);

    constexpr int NP = NSTEPS / 2;
#pragma unroll 1
    for (int p = 0; p < NP; ++p) {
        const int ks = 2 * p;
        asm volatile("s_waitcnt vmcnt(6)" ::: "memory");
        __builtin_amdgcn_s_barrier();
        __builtin_amdgcn_sched_barrier(0);
        if (ks + 2 < NSTEPS) stageA(ks + 2, (ks + 2) % 3);
        loadB(bfo, ks + 1);
        compute(ks, bfe);
        if (p == NP - 1) asm volatile("s_waitcnt vmcnt(0)" ::: "memory");
        else             asm volatile("s_waitcnt vmcnt(6)" ::: "memory");
        __builtin_amdgcn_s_barrier();
        __builtin_amdgcn_sched_barrier(0);
        if (ks + 3 < NSTEPS) stageA(ks + 3, (ks + 3) % 3);
        if (ks + 2 < NSTEPS) loadB(bfe, ks + 2);
        compute(ks + 1, bfo);
    }

    // ---- C-write via LDS: 32 rows x 528B-stride bf16 tile, 2 halves ----
    unsigned char* tile = &As[0][0];        // 32*528 = 16896B < 24576B
    const int cbase = w * 64;
    __syncthreads();                        // all LDS reads of K-loop done
#pragma unroll 1
    for (int half = 0; half < 2; ++half) {
#pragma unroll
        for (int fr2 = 0; fr2 < 2; ++fr2) {
            int fr = half * 2 + fr2;
#pragma unroll
            for (int reg = 0; reg < 4; ++reg) {
                int rloc = fr2 * 16 + g * 4 + reg;          // 0..31
                int grow = m0 + half * 32 + rloc;
#pragma unroll
                for (int fc = 0; fc < 4; ++fc) {
                    float vv = acc[fr][fc][reg];
                    if (grow == 0) vv = 0.f;
                    int col = cbase + fc * 16 + rl;
                    *(__hip_bfloat16*)(tile + rloc * 528 + col * 2) = __float2bfloat16(vv);
                }
            }
        }
        __syncthreads();
        // packed store: 32 rows x 32 chunks(16B) = 1024 chunks, 4 per thread
#pragma unroll
        for (int j = 0; j < 4; ++j) {
            int ci = j * 256 + t;
            int r = ci >> 5, c = ci & 31;
            int grow = m0 + half * 32 + r;
            if (grow < N) {
                short8 v = *(const short8*)(tile + r * 528 + c * 16);
                *(short8*)(h0b + (size_t)grow * 256 + c * 8) = v;
            }
        }
        __syncthreads();
    }
}

// kg1: out = LN(h0b + S@wp2), row 0 zeroed. A = S bf16 [N][768], R8 structure.
__global__ __launch_bounds__(256, 4) void kg1(
    const __hip_bfloat16* __restrict__ Sb,
    const __hip_bfloat16* __restrict__ wp,
    const __hip_bfloat16* __restrict__ h0b,
    const float* __restrict__ gamma, const float* __restrict__ beta,
    float* __restrict__ out, int N)
{
    constexpr int NSTEPS = 24;
    __shared__ __align__(16) unsigned char As[3][4096];
    __shared__ float redS[64][4];
    __shared__ float redQ[64][4];

    const int t = threadIdx.x;
    const int lane = t & 63;
    const int w = t >> 6;
    const int m0 = blockIdx.x * 64;
    const int g = lane >> 4;
    const int rl = lane & 15;

    auto stageA = [&](int ks, int buf) {
        int r = w * 16 + (lane >> 2);
        int grow = m0 + r; if (grow >= N) grow = m0;
        int q = (lane & 3) ^ ((lane >> 3) & 3);
        const __hip_bfloat16* src = Sb + (size_t)grow * 768 + ks * 32 + q * 8;
        gld16(src, As[buf] + w * 1024);
    };
    auto loadB = [&](short8 (&bf)[4], int ks) {
#pragma unroll
        for (int fc = 0; fc < 4; ++fc)
            bf[fc] = *(const short8*)((const short*)wp +
                      (size_t)(ks * 256 + w * 64 + fc * 16 + rl) * 32 + g * 8);
    };

    f32x4 acc[4][4];
#pragma unroll
    for (int i = 0; i < 4; ++i)
#pragma unroll
        for (int j = 0; j < 4; ++j) acc[i][j] = (f32x4){0.f, 0.f, 0.f, 0.f};

    auto compute = [&](int ks, short8 (&bf)[4]) {
        const unsigned char* Ab = As[ks % 3];
        short8 af[4];
#pragma unroll
        for (int fr = 0; fr < 4; ++fr) {
            int r = fr * 16 + rl;
            af[fr] = *(const short8*)(Ab + r * 64 + (g ^ ((r >> 1) & 3)) * 16);
        }
#pragma unroll
        for (int fr = 0; fr < 4; ++fr)
#pragma unroll
            for (int fc = 0; fc < 4; ++fc)
                acc[fr][fc] = __builtin_amdgcn_mfma_f32_16x16x32_bf16(af[fr], bf[fc], acc[fr][fc], 0, 0, 0);
    };

    short8 bfe[4], bfo[4];
    stageA(0, 0);
    stageA(1, 1);
    loadB(bfe, 0);

    constexpr int NP = NSTEPS / 2;
#pragma unroll 1
    for (int p = 0; p < NP; ++p) {
        const int ks = 2 * p;
        asm volatile("s_waitcnt vmcnt(5)" ::: "memory");
        __builtin_amdgcn_s_barrier();
        __builtin_amdgcn_sched_barrier(0);
        if (ks + 2 < NSTEPS) stageA(ks + 2, (ks + 2) % 3);
        loadB(bfo, ks + 1);
        compute(ks, bfe);
        if (p == NP - 1) asm volatile("s_waitcnt vmcnt(0)" ::: "memory");
        else             asm volatile("s_waitcnt vmcnt(5)" ::: "memory");
        __builtin_amdgcn_s_barrier();
        __builtin_amdgcn_sched_barrier(0);
        if (ks + 3 < NSTEPS) stageA(ks + 3, (ks + 3) % 3);
        if (ks + 2 < NSTEPS) loadB(bfe, ks + 2);
        compute(ks + 1, bfo);
    }

    const int cbase = w * 64;
    // residual from bf16 h0
#pragma unroll
    for (int fr = 0; fr < 4; ++fr)
#pragma unroll
        for (int reg = 0; reg < 4; ++reg) {
            int grow = m0 + fr * 16 + g * 4 + reg;
            if (grow < N) {
#pragma unroll
                for (int fc = 0; fc < 4; ++fc)
                    acc[fr][fc][reg] +=
                        __bfloat162float(h0b[(size_t)grow * 256 + cbase + fc * 16 + rl]);
            }
        }
#pragma unroll
    for (int fr = 0; fr < 4; ++fr)
#pragma unroll
        for (int reg = 0; reg < 4; ++reg) {
            float s = 0.f, q = 0.f;
#pragma unroll
            for (int fc = 0; fc < 4; ++fc) {
                float vv = acc[fr][fc][reg];
                s += vv; q += vv * vv;
            }
#pragma unroll
            for (int off = 1; off < 16; off <<= 1) {
                s += __shfl_xor(s, off, 64);
                q += __shfl_xor(q, off, 64);
            }
            if (rl == 0) {
                int rli = fr * 16 + g * 4 + reg;
                redS[rli][w] = s;
                redQ[rli][w] = q;
            }
        }
    __syncthreads();
    float g4[4], b4[4];
#pragma unroll
    for (int fc = 0; fc < 4; ++fc) {
        g4[fc] = gamma[cbase + fc * 16 + rl];
        b4[fc] = beta[cbase + fc * 16 + rl];
    }
#pragma unroll
    for (int fr = 0; fr < 4; ++fr)
#pragma unroll
        for (int reg = 0; reg < 4; ++reg) {
            int rli = fr * 16 + g * 4 + reg;
            int grow = m0 + rli;
            if (grow >= N) continue;
            float s = redS[rli][0] + redS[rli][1] + redS[rli][2] + redS[rli][3];
            float q = redQ[rli][0] + redQ[rli][1] + redQ[rli][2] + redQ[rli][3];
            float mu  = s * (1.f / 256.f);
            float var = q * (1.f / 256.f) - mu * mu;
            float rstd = rsqrtf(var + LN_EPS);
#pragma unroll
            for (int fc = 0; fc < 4; ++fc) {
                float vv = (acc[fr][fc][reg] - mu) * rstd * g4[fc] + b4[fc];
                if (grow == 0) vv = 0.f;
                out[(size_t)grow * 256 + cbase + fc * 16 + rl] = vv;
            }
        }
}

extern "C" void kernel_launch(void* const* d_in, const int* in_sizes, int n_in,
                              void* d_out, int out_size, void* d_ws, size_t ws_size,
                              hipStream_t stream) {
    const int N = in_sizes[0] / 384;   // 100000
    const int E = in_sizes[7];         // 300000
    const float* ft    = (const float*)d_in[0];
    const float* fi    = (const float*)d_in[1];
    const float* wt    = (const float*)d_in[2];
    const float* wi    = (const float*)d_in[3];
    const float* wrel  = (const float*)d_in[4];
    const float* gamma = (const float*)d_in[5];
    const float* beta  = (const float*)d_in[6];
    const float* ew    = (const float*)d_in[7];
    const int*   eidx  = (const int*)d_in[8];
    const int*   etype = (const int*)d_in[9];
    float* out = (float*)d_out;

    // ws: S bf16 [N][768] | h0b bf16 [N][256] | head int[N] | nxt int[E] | wp1 | wp2
    __hip_bfloat16* S   = (__hip_bfloat16*)d_ws;
    __hip_bfloat16* h0b = S + (size_t)N * 768;
    int* head = (int*)(h0b + (size_t)N * 256);
    int* nxt  = head + N;
    __hip_bfloat16* wp1 = (__hip_bfloat16*)(nxt + E);
    __hip_bfloat16* wp2 = wp1 + WP1_ELEMS;

    hipMemsetAsync(head, 0xFF, (size_t)N * sizeof(int), stream);

    kpack<<<(WP1_ELEMS + WP2_ELEMS + 255) / 256, 256, 0, stream>>>(wt, wi, wrel, wp1, wp2);

    kchain<<<(E + 255) / 256, 256, 0, stream>>>(eidx + E, head, nxt, E);

    const int gblocks = (N + 63) / 64;                   // 1563
    kg0<<<gblocks, 256, 0, stream>>>(ft, fi, wp1, h0b, N);

    k2_gather<<<(N + 7) / 8, 512, 0, stream>>>(h0b, eidx, etype, ew, head, nxt, S, N);

    kg1<<<gblocks, 256, 0, stream>>>(S, wp2, h0b, gamma, beta, out, N);
}